// Round 7
// baseline (444.084 us; speedup 1.0000x reference)
//
#include <hip/hip_runtime.h>
#include <math.h>

#define Bb 4
#define Hh 128
#define Ww 256
#define Cc 64
#define Ff 128
#define INH 130   // H+2
#define INW 258   // W+2

#define WSLOT 72   // shorts per slot: 64 bf16 + 8 pad = 144B (36 words, ≡4 mod 32 banks)
#define WPW 37     // slots per wave window: 0..35 data, 36 = zero slot

typedef __attribute__((ext_vector_type(8))) __bf16 bf16x8;
typedef __attribute__((ext_vector_type(4))) float floatx4;

__device__ __forceinline__ unsigned short f2bf(float f) {
  unsigned int u = __float_as_uint(f);
  unsigned int r = u + 0x7fffu + ((u >> 16) & 1u);   // RNE
  return (unsigned short)(r >> 16);
}

// v_cvt_pk_bf16_f32: D[15:0]=bf16(S0), D[31:16]=bf16(S1), RNE.
__device__ __forceinline__ unsigned int cvt_pk_bf16(float lo, float hi) {
  unsigned int r;
  asm("v_cvt_pk_bf16_f32 %0, %1, %2" : "=v"(r) : "v"(lo), "v"(hi));
  return r;
}

// ---------------------------------------------------------------------------
// Prep: kernel -> bf16 in MFMA-fragment order kTB[tap][kk][quad][f] (16B per
// (..,f) chunk -> B-frag loads are 16B/lane fully-coalesced), + fp64 offset
// table (fp32 would flip the ux>0 branch at h=0).
// ---------------------------------------------------------------------------
__global__ void prep_kernel(const float* __restrict__ kmat,
                            float* __restrict__ offtab,
                            unsigned short* __restrict__ kTB) {
  int gid = blockIdx.x * 256 + threadIdx.x;
  if (gid < 576 * 128) {
    int f = gid & 127;
    int k = gid >> 7;
    int tap = k >> 6;
    int r = k & 63;
    int kk = r >> 5;
    int quad = (r >> 3) & 3;
    int i = r & 7;
    int chunk = tap * 8 + kk * 4 + quad;
    kTB[((size_t)chunk * 128 + f) * 8 + i] = f2bf(kmat[gid]);
  }
  if (gid < Hh * 9) {
    int h = gid / 9;
    int j = gid - h * 9;
    const double pi = 3.14159265358979323846;
    double unit_w = 2.0 * pi / (double)Ww;
    double unit_h = pi / (2.0 * (double)Hh);
    double rho = tan(unit_w);
    double theta = ((double)(Ww / 2) - 0.5 * (double)Ww) * unit_w;
    double phi = ((double)Hh - (double)h) * unit_h;
    double cph = cos(phi), sph = sin(phi);
    double cth = cos(theta), sth = sin(theta);
    double pux = cph * cth, puy = sph, puz = cph * sth;
    double txx = puz, txy = 0.0, txz = -pux;
    double tyx = puy * txz - puz * txy;
    double tyy = puz * txx - pux * txz;
    double tyz = pux * txy - puy * txx;
    const int r0t[9] = {1, 1, 1, 0, 0, 0, -1, -1, -1};
    const int r1t[9] = {-1, 0, 1, -1, 0, 1, -1, 0, 1};
    auto proj = [&](int r0, int r1, double& xr, double& yr) {
      double ux = pux + rho * ((double)r0 * txx + (double)r1 * tyx);
      double uy = puy + rho * ((double)r0 * txy + (double)r1 * tyy);
      double uz = puz + rho * ((double)r0 * txz + (double)r1 * tyz);
      double base = atan2(uz, ux);
      double th;
      if (ux > 0.0)        th = base;
      else if (ux < 0.0)   th = (uz >= 0.0) ? base + pi : base - pi;
      else                 th = (uz > 0.0) ? pi * 0.5 : -pi * 0.5;
      double ph = asin(uy);
      xr = (th / pi + 1.0) * 0.5 * (double)Ww;
      yr = (1.0 - 2.0 * ph / pi) * (double)Hh;
    };
    double xc, yc, xj, yj;
    proj(0, 0, xc, yc);
    proj(r0t[j], r1t[j], xj, yj);
    offtab[gid * 2 + 0] = (float)(xj - xc);   // added to y (faithful swap)
    offtab[gid * 2 + 1] = (float)(yj - yc);   // added to x
  }
}

// ---------------------------------------------------------------------------
// Fused, TAP-SPLIT + bf16 Y-BLEND WINDOW: per (b,h,64-w tile), 4 waves =
// {2 m-ranges} x {tap-groups 0-4 / 5-8}. Total waves double to 32/CU of
// work; bf16 window (5.3KB/wave, 21.3KB/block) -> 7 blocks/CU resident =
// 28 waves/CU (the R6 structure was grid-capped at 16). Per-wave serial
// chain halves (4-5 taps). bf16 16B-task geometry makes BOTH the fill
// ds_write (start=4*ls+4*(l&7)) and the A-frag ds_read (start=4*ls+16kk+4q)
// conflict-free (each consecutive-8-lane group tiles all 32 banks) -- R6's
// fp32 pattern had 5.0M conflicts. Zero barriers in the tap loop (private
// windows, same-wave in-order DS, R5/R6-proven); 8 epilogue barriers for
// the chunked pair-reduction through reused window LDS.
// Numerics: y-blend fp32 -> bf16 (RNE) -> x-blend fp32 -> bf16 (RNE): one
// extra rounding vs R6; absmax may rise ~1.4x (declared risk).
// ---------------------------------------------------------------------------
__global__ __launch_bounds__(256, 7) void fused_kernel(
    const float* __restrict__ in, const float* __restrict__ bias,
    const unsigned short* __restrict__ kTB, const float* __restrict__ offtab,
    float* __restrict__ out) {
  __shared__ unsigned short winH[4 * WPW * WSLOT];   // 21,312 B -> 7 blocks/CU

  // XCD swizzle: 2048 blocks; each XCD serves a contiguous (b, h-slice)
  int lidx = ((blockIdx.x & 7) << 8) | (blockIdx.x >> 3);
  int wt = lidx & 3;
  int h  = (lidx >> 2) & 127;
  int b  = lidx >> 9;
  int w0 = wt << 6;

  int tid  = threadIdx.x;
  int lane = tid & 63;
  int wave = tid >> 6;
  int mr   = wave & 1;             // m-range within the 64-w tile
  int tg   = wave >> 1;            // tap group: 0 -> taps 0..4, 1 -> taps 5..8
  int m_base = mr << 5;
  int l15  = lane & 15;
  int quad = lane >> 4;

  unsigned short* win = &winH[wave * (WPW * WSLOT)];
  // zero the private zero-slot (slot 36): 144 B
  if (lane < 9) *(uint4*)&win[36 * WSLOT + lane * 8] = (uint4){0u, 0u, 0u, 0u};
  // no barrier: only this wave reads it; same-wave DS ops are in-order

  floatx4 acc[2][8];
#pragma unroll
  for (int i = 0; i < 2; i++)
#pragma unroll
    for (int j = 0; j < 8; j++) acc[i][j] = (floatx4){0.f, 0.f, 0.f, 0.f};

  const float* inb = in + (size_t)b * Hh * Ww * Cc;
  const bf16x8* kbase = (const bf16x8*)kTB;

  int tapA = tg ? 5 : 0;
  int tapB = tg ? 9 : 5;
  for (int tap = tapA; tap < tapB; tap++) {
    float off0 = offtab[(h * 9 + tap) * 2 + 0];
    float off1 = offtab[(h * 9 + tap) * 2 + 1];
    float dyk = (float)(tap / 3), dxk = (float)(tap % 3);

    // ---- y side (block-uniform): rows + weights, pad folded into weights ----
    float y = (float)h + dyk + off0;
    y = fminf(fmaxf(y, 0.f), (float)(INH - 1));
    int y0i = (int)floorf(y);
    int y1i = y0i + 1;
    y0i = min(max(y0i, 0), INH - 1);
    y1i = min(max(y1i, 0), INH - 1);
    float wy0 = (float)y1i - y;
    float wy1 = y - (float)y0i;
    if (!(y0i >= 1 && y0i <= Hh)) wy0 = 0.f;
    if (!(y1i >= 1 && y1i <= Hh)) wy1 = 0.f;
    const char* r0 = (const char*)(inb + (size_t)min(max(y0i - 1, 0), Hh - 1) * Ww * Cc);
    const char* r1 = (const char*)(inb + (size_t)min(max(y1i - 1, 0), Hh - 1) * Ww * Cc);

    // ---- x side: block-uniform frac + window base ----
    float xrep = (float)w0 + dxk + off1;
    float flo  = floorf(xrep);
    int jb = (int)flo - 1;
    float fr = xrep - flo;              // uniform frac across w (±1ulp, benign)
    float fxa = 1.f - fr, fxb = fr;

    // ---- per-lane slot pairs (local to this wave's window) ----
    int s0v[2], s1v[2];
#pragma unroll
    for (int mi = 0; mi < 2; mi++) {
      int wr = m_base + mi * 16 + l15;
      float x = (float)(w0 + wr) + dxk + off1;   // ref op order
      if (x < 0.f) x += (float)INW;
      if (x > (float)(INW - 1)) x -= (float)INW;
      int x0i = (int)floorf(x);
      int s = x0i - jb;
      if (s < 0) s += INW;              // single-wrap lanes -> mod lookup
      int ls = s - m_base;              // expected = (mi*16+l15)+1 in [1,33]
      bool ok = (unsigned)ls <= 34u;    // margin for ±1ulp jitter
      s0v[mi] = ok ? ls : 36;           // outside window -> zero slot (both)
      s1v[mi] = ok ? ls + 1 : 36;
    }

    // ---- fill OWN window with Y-BLEND (bf16): 36 slots x 8 ch-groups =
    //      288 tasks; coalesced loads (8 lanes x consecutive 32B of one
    //      column); ONE column read per slot; ONE 16B ds_write per task,
    //      conflict-free (start = 4*ls + 4*(l&7) tiles banks) ----
#pragma unroll
    for (int it = 0; it < 5; it++) {
      int t = lane + (it << 6);
      if (it < 4 || lane < 32) {        // 288 tasks
        int ls = t >> 3;
        int c8f = (t & 7) << 3;                 // float channel base
        int col = jb + m_base + ls;             // global raw column
        if (col < 0) col += INW;
        if (col > INW - 1) col -= INW;          // col in [0,257]
        bool cok = ((unsigned)(col - 1) < (unsigned)Ww);
        unsigned offc = (((unsigned)((col - 1) & (Ww - 1))) << 8) + ((unsigned)c8f << 2);
        float wa = cok ? wy0 : 0.f;             // x-pad -> zero column
        float wb = cok ? wy1 : 0.f;
        float4 a0 = *(const float4*)(r0 + offc);
        float4 a1 = *(const float4*)(r0 + offc + 16);
        float4 b0 = *(const float4*)(r1 + offc);
        float4 b1 = *(const float4*)(r1 + offc + 16);
        uint4 st;
        st.x = cvt_pk_bf16(wa * a0.x + wb * b0.x, wa * a0.y + wb * b0.y);
        st.y = cvt_pk_bf16(wa * a0.z + wb * b0.z, wa * a0.w + wb * b0.w);
        st.z = cvt_pk_bf16(wa * a1.x + wb * b1.x, wa * a1.y + wb * b1.y);
        st.w = cvt_pk_bf16(wa * a1.z + wb * b1.z, wa * a1.w + wb * b1.w);
        *(uint4*)(&win[ls * WSLOT + ((t & 7) << 3)]) = st;   // 16B ds_write_b128
      }
    }

    // ---- MFMA: A-frags x-blended from OWN window (in-order DS = fill
    //      done); reads conflict-free; B-frags coalesced from L2-hot kTB,
    //      each feeds both mi ----
#pragma unroll
    for (int kk = 0; kk < 2; kk++) {
      int ch0 = (tap * 8 + kk * 4 + quad) * 128;
      bf16x8 bfrag[8];
#pragma unroll
      for (int ni = 0; ni < 8; ni++)
        bfrag[ni] = kbase[ch0 + ni * 16 + l15];
      bf16x8 af[2];
#pragma unroll
      for (int mi = 0; mi < 2; mi++) {
        uint4 ua = *(const uint4*)&win[s0v[mi] * WSLOT + kk * 32 + quad * 8];
        uint4 ub = *(const uint4*)&win[s1v[mi] * WSLOT + kk * 32 + quad * 8];
        union { uint4 u; bf16x8 v; } afc;
        {
          float a0 = __uint_as_float(ua.x << 16), a1 = __uint_as_float(ua.x & 0xffff0000u);
          float c0 = __uint_as_float(ub.x << 16), c1 = __uint_as_float(ub.x & 0xffff0000u);
          afc.u.x = cvt_pk_bf16(fxa * a0 + fxb * c0, fxa * a1 + fxb * c1);
        }
        {
          float a0 = __uint_as_float(ua.y << 16), a1 = __uint_as_float(ua.y & 0xffff0000u);
          float c0 = __uint_as_float(ub.y << 16), c1 = __uint_as_float(ub.y & 0xffff0000u);
          afc.u.y = cvt_pk_bf16(fxa * a0 + fxb * c0, fxa * a1 + fxb * c1);
        }
        {
          float a0 = __uint_as_float(ua.z << 16), a1 = __uint_as_float(ua.z & 0xffff0000u);
          float c0 = __uint_as_float(ub.z << 16), c1 = __uint_as_float(ub.z & 0xffff0000u);
          afc.u.z = cvt_pk_bf16(fxa * a0 + fxb * c0, fxa * a1 + fxb * c1);
        }
        {
          float a0 = __uint_as_float(ua.w << 16), a1 = __uint_as_float(ua.w & 0xffff0000u);
          float c0 = __uint_as_float(ub.w << 16), c1 = __uint_as_float(ub.w & 0xffff0000u);
          afc.u.w = cvt_pk_bf16(fxa * a0 + fxb * c0, fxa * a1 + fxb * c1);
        }
        af[mi] = afc.v;
      }
#pragma unroll
      for (int ni = 0; ni < 8; ni++) {
        acc[0][ni] = __builtin_amdgcn_mfma_f32_16x16x32_bf16(af[0], bfrag[ni], acc[0][ni], 0, 0, 0);
        acc[1][ni] = __builtin_amdgcn_mfma_f32_16x16x32_bf16(af[1], bfrag[ni], acc[1][ni], 0, 0, 0);
      }
    }
    // no barrier: next tap's fill overwrites only THIS wave's window after
    // this wave's reads (same-wave DS ops execute in issue order)
  }

  // ---- tap-group reduction (epilogue only): pair (mr): tg1's acc summed
  //      into tg0's, 4 chunks of 2 ni through tg1's (dead) window; then
  //      bias+relu+store by tg0 (C/D: col=lane&15, row=quad*4+r) ----
  float* redbuf = (float*)&winH[(2 + mr) * (WPW * WSLOT)];   // 4KB used of 5.3KB
  size_t outbase = ((size_t)(b * Hh + h) * Ww + w0);
#pragma unroll
  for (int c = 0; c < 4; c++) {
    __syncthreads();
    if (tg == 1) {
#pragma unroll
      for (int mi = 0; mi < 2; mi++)
#pragma unroll
        for (int j = 0; j < 2; j++)
          *(floatx4*)&redbuf[(mi * 2 + j) * 256 + lane * 4] = acc[mi][2 * c + j];
    }
    __syncthreads();
    if (tg == 0) {
#pragma unroll
      for (int mi = 0; mi < 2; mi++)
#pragma unroll
        for (int j = 0; j < 2; j++) {
          floatx4 other = *(const floatx4*)&redbuf[(mi * 2 + j) * 256 + lane * 4];
          int ni = 2 * c + j;
          int f = ni * 16 + l15;
          float bv = bias[f];
#pragma unroll
          for (int r = 0; r < 4; r++) {
            int m = m_base + mi * 16 + quad * 4 + r;
            out[(outbase + m) * Ff + f] = fmaxf(acc[mi][ni][r] + other[r] + bv, 0.f);
          }
        }
    }
  }
}

extern "C" void kernel_launch(void* const* d_in, const int* in_sizes, int n_in,
                              void* d_out, int out_size, void* d_ws, size_t ws_size,
                              hipStream_t stream) {
  const float* in   = (const float*)d_in[0];
  const float* kmat = (const float*)d_in[1];
  const float* bias = (const float*)d_in[2];
  float* out = (float*)d_out;

  float* offtab = (float*)d_ws;
  unsigned short* kTB = (unsigned short*)((char*)d_ws + Hh * 9 * 2 * sizeof(float));
  if (ws_size < (size_t)(Hh * 9 * 2 * sizeof(float) + 128 * 576 * sizeof(unsigned short)))
    return;

  prep_kernel<<<288, 256, 0, stream>>>(kmat, offtab, kTB);
  fused_kernel<<<Bb * Hh * (Ww / 64), 256, 0, stream>>>(in, bias, kTB, offtab, out);
}

// Round 8
// 163.822 us; speedup vs baseline: 2.7108x; 2.7108x over previous
//
#include <hip/hip_runtime.h>
#include <math.h>

#define Bb 4
#define Hh 128
#define Ww 256
#define Cc 64
#define Ff 128
#define INH 130   // H+2
#define INW 258   // W+2

#define WSLOT 72   // shorts per slot: 64 bf16 + 8 pad = 144B
#define WPW 37     // slots per window: 0..35 data, 36 = zero slot

typedef __attribute__((ext_vector_type(8))) __bf16 bf16x8;
typedef __attribute__((ext_vector_type(4))) float floatx4;

__device__ __forceinline__ unsigned short f2bf(float f) {
  unsigned int u = __float_as_uint(f);
  unsigned int r = u + 0x7fffu + ((u >> 16) & 1u);   // RNE
  return (unsigned short)(r >> 16);
}

// v_cvt_pk_bf16_f32: D[15:0]=bf16(S0), D[31:16]=bf16(S1), RNE.
__device__ __forceinline__ unsigned int cvt_pk_bf16(float lo, float hi) {
  unsigned int r;
  asm("v_cvt_pk_bf16_f32 %0, %1, %2" : "=v"(r) : "v"(lo), "v"(hi));
  return r;
}

// ---------------------------------------------------------------------------
// Prep: kernel -> bf16 in MFMA-fragment order kTB[tap][kk][quad][f] (16B per
// (..,f) chunk -> B-frag loads are 16B/lane fully-coalesced), + fp64 offset
// table (fp32 would flip the ux>0 branch at h=0).
// ---------------------------------------------------------------------------
__global__ void prep_kernel(const float* __restrict__ kmat,
                            float* __restrict__ offtab,
                            unsigned short* __restrict__ kTB) {
  int gid = blockIdx.x * 256 + threadIdx.x;
  if (gid < 576 * 128) {
    int f = gid & 127;
    int k = gid >> 7;
    int tap = k >> 6;
    int r = k & 63;
    int kk = r >> 5;
    int quad = (r >> 3) & 3;
    int i = r & 7;
    int chunk = tap * 8 + kk * 4 + quad;
    kTB[((size_t)chunk * 128 + f) * 8 + i] = f2bf(kmat[gid]);
  }
  if (gid < Hh * 9) {
    int h = gid / 9;
    int j = gid - h * 9;
    const double pi = 3.14159265358979323846;
    double unit_w = 2.0 * pi / (double)Ww;
    double unit_h = pi / (2.0 * (double)Hh);
    double rho = tan(unit_w);
    double theta = ((double)(Ww / 2) - 0.5 * (double)Ww) * unit_w;
    double phi = ((double)Hh - (double)h) * unit_h;
    double cph = cos(phi), sph = sin(phi);
    double cth = cos(theta), sth = sin(theta);
    double pux = cph * cth, puy = sph, puz = cph * sth;
    double txx = puz, txy = 0.0, txz = -pux;
    double tyx = puy * txz - puz * txy;
    double tyy = puz * txx - pux * txz;
    double tyz = pux * txy - puy * txx;
    const int r0t[9] = {1, 1, 1, 0, 0, 0, -1, -1, -1};
    const int r1t[9] = {-1, 0, 1, -1, 0, 1, -1, 0, 1};
    auto proj = [&](int r0, int r1, double& xr, double& yr) {
      double ux = pux + rho * ((double)r0 * txx + (double)r1 * tyx);
      double uy = puy + rho * ((double)r0 * txy + (double)r1 * tyy);
      double uz = puz + rho * ((double)r0 * txz + (double)r1 * tyz);
      double base = atan2(uz, ux);
      double th;
      if (ux > 0.0)        th = base;
      else if (ux < 0.0)   th = (uz >= 0.0) ? base + pi : base - pi;
      else                 th = (uz > 0.0) ? pi * 0.5 : -pi * 0.5;
      double ph = asin(uy);
      xr = (th / pi + 1.0) * 0.5 * (double)Ww;
      yr = (1.0 - 2.0 * ph / pi) * (double)Hh;
    };
    double xc, yc, xj, yj;
    proj(0, 0, xc, yc);
    proj(r0t[j], r1t[j], xj, yj);
    offtab[gid * 2 + 0] = (float)(xj - xc);   // added to y (faithful swap)
    offtab[gid * 2 + 1] = (float)(yj - yc);   // added to x
  }
}

// ---------------------------------------------------------------------------
// Fused, N-SPLIT COOPERATIVE: per (b,h,64-w tile), 4 waves = {2 m-ranges} x
// {2 f-halves}. acc[2][4]=32 AGPR + ~60 VGPR ≈ 95 unified -> 5 waves/SIMD
// (pool is 512/SIMD; R7's (256,7) demanded 73 and spilled 1.4GB).
// The 2 waves sharing an m-range cooperatively fill ONE shared bf16 y-blend
// window (144 tasks each: per-wave fill chain HALVES, total fill VMEM
// unchanged). bf16 window numerics + conflict-free 16B-task LDS geometry
// proven in R7 (absmax unchanged). Cross-wave sharing -> 1 __syncthreads
// per tap with double-buffered windows (write buf[t^1] next iter; all
// waves' reads of buf[t] precede their barrier(t+1)). Epilogue barrier-free
// (disjoint (m,f) ownership). Grid 2048 -> 5 blocks/CU = 20 waves/CU with
// decorrelated convoy phases.
// ---------------------------------------------------------------------------
__global__ __launch_bounds__(256, 5) void fused_kernel(
    const float* __restrict__ in, const float* __restrict__ bias,
    const unsigned short* __restrict__ kTB, const float* __restrict__ offtab,
    float* __restrict__ out) {
  __shared__ unsigned short winH[4 * WPW * WSLOT];   // [buf][mr], 21,312 B

  // XCD swizzle: each XCD serves one b-ish contiguous (b, 64-h slice) ~ L2
  int lidx = ((blockIdx.x & 7) << 8) | (blockIdx.x >> 3);
  int wt = lidx & 3;
  int h  = (lidx >> 2) & 127;
  int b  = lidx >> 9;
  int w0 = wt << 6;

  int tid  = threadIdx.x;
  int lane = tid & 63;
  int wave = tid >> 6;
  int mr   = wave & 1;             // m-range: rows [mr*32, mr*32+32)
  int ng   = wave >> 1;            // f-half:  cols [ng*64, ng*64+64)
  int m_base = mr << 5;
  int l15  = lane & 15;
  int quad = lane >> 4;

  // zero slot 36 of all 4 windows (wave (ng,mr) -> window [ng][mr]);
  // visible to partner wave after the tap-0 barrier
  if (lane < 9)
    *(uint4*)&winH[((ng << 1) | mr) * (WPW * WSLOT) + 36 * WSLOT + lane * 8] =
        (uint4){0u, 0u, 0u, 0u};

  floatx4 acc[2][4];
#pragma unroll
  for (int i = 0; i < 2; i++)
#pragma unroll
    for (int j = 0; j < 4; j++) acc[i][j] = (floatx4){0.f, 0.f, 0.f, 0.f};

  const float* inb = in + (size_t)b * Hh * Ww * Cc;
  const bf16x8* kbase = (const bf16x8*)kTB;

  for (int tap = 0; tap < 9; tap++) {
    float off0 = offtab[(h * 9 + tap) * 2 + 0];
    float off1 = offtab[(h * 9 + tap) * 2 + 1];
    float dyk = (float)(tap / 3), dxk = (float)(tap % 3);

    // ---- y side (block-uniform): rows + weights, pad folded into weights ----
    float y = (float)h + dyk + off0;
    y = fminf(fmaxf(y, 0.f), (float)(INH - 1));
    int y0i = (int)floorf(y);
    int y1i = y0i + 1;
    y0i = min(max(y0i, 0), INH - 1);
    y1i = min(max(y1i, 0), INH - 1);
    float wy0 = (float)y1i - y;
    float wy1 = y - (float)y0i;
    if (!(y0i >= 1 && y0i <= Hh)) wy0 = 0.f;
    if (!(y1i >= 1 && y1i <= Hh)) wy1 = 0.f;
    const char* r0 = (const char*)(inb + (size_t)min(max(y0i - 1, 0), Hh - 1) * Ww * Cc);
    const char* r1 = (const char*)(inb + (size_t)min(max(y1i - 1, 0), Hh - 1) * Ww * Cc);

    // ---- x side: block-uniform frac + window base ----
    float xrep = (float)w0 + dxk + off1;
    float flo  = floorf(xrep);
    int jb = (int)flo - 1;
    float fr = xrep - flo;              // uniform frac across w (±1ulp, benign)
    float fxa = 1.f - fr, fxb = fr;

    // ---- per-lane slot pairs (within this m-range's window) ----
    int s0v[2], s1v[2];
#pragma unroll
    for (int mi = 0; mi < 2; mi++) {
      int wr = m_base + mi * 16 + l15;
      float x = (float)(w0 + wr) + dxk + off1;   // ref op order
      if (x < 0.f) x += (float)INW;
      if (x > (float)(INW - 1)) x -= (float)INW;
      int x0i = (int)floorf(x);
      int s = x0i - jb;
      if (s < 0) s += INW;              // single-wrap lanes -> mod lookup
      int ls = s - m_base;              // expected = (mi*16+l15)+1 in [1,33]
      bool ok = (unsigned)ls <= 34u;    // margin for ±1ulp jitter
      s0v[mi] = ok ? ls : 36;           // outside window -> zero slot (both)
      s1v[mi] = ok ? ls + 1 : 36;
    }

    unsigned short* win = &winH[(((tap & 1) << 1) | mr) * (WPW * WSLOT)];

    // ---- cooperative fill of shared window[mr] (bf16 y-blend): 288 tasks
    //      split by ng: this wave does tasks [ng*144, ng*144+144).
    //      Coalesced loads (8 lanes x consecutive 32B of one column); ONE
    //      column read per slot; one conflict-free 16B ds_write per task ----
#pragma unroll
    for (int it = 0; it < 3; it++) {
      if (it < 2 || lane < 16) {
        int t = ng * 144 + (it << 6) + lane;
        int ls = t >> 3;
        int c8f = (t & 7) << 3;                 // float channel base
        int col = jb + m_base + ls;             // global raw column
        if (col < 0) col += INW;
        if (col > INW - 1) col -= INW;          // col in [0,257]
        bool cok = ((unsigned)(col - 1) < (unsigned)Ww);
        unsigned offc = (((unsigned)((col - 1) & (Ww - 1))) << 8) + ((unsigned)c8f << 2);
        float wa = cok ? wy0 : 0.f;             // x-pad -> zero column
        float wb = cok ? wy1 : 0.f;
        float4 a0 = *(const float4*)(r0 + offc);
        float4 a1 = *(const float4*)(r0 + offc + 16);
        float4 b0 = *(const float4*)(r1 + offc);
        float4 b1 = *(const float4*)(r1 + offc + 16);
        uint4 st;
        st.x = cvt_pk_bf16(wa * a0.x + wb * b0.x, wa * a0.y + wb * b0.y);
        st.y = cvt_pk_bf16(wa * a0.z + wb * b0.z, wa * a0.w + wb * b0.w);
        st.z = cvt_pk_bf16(wa * a1.x + wb * b1.x, wa * a1.y + wb * b1.y);
        st.w = cvt_pk_bf16(wa * a1.z + wb * b1.z, wa * a1.w + wb * b1.w);
        *(uint4*)(&win[ls * WSLOT + ((t & 7) << 3)]) = st;   // ds_write_b128
      }
    }

    __syncthreads();   // window[mr] complete; dbuf makes 1 barrier/tap safe

    // ---- MFMA: A-frags x-blended from shared window; B-frags coalesced
    //      from L2-hot kTB (this wave's f-half); 8 MFMA/tap ----
#pragma unroll
    for (int kk = 0; kk < 2; kk++) {
      bf16x8 af[2];
#pragma unroll
      for (int mi = 0; mi < 2; mi++) {
        uint4 ua = *(const uint4*)&win[s0v[mi] * WSLOT + kk * 32 + quad * 8];
        uint4 ub = *(const uint4*)&win[s1v[mi] * WSLOT + kk * 32 + quad * 8];
        union { uint4 u; bf16x8 v; } afc;
        {
          float a0 = __uint_as_float(ua.x << 16), a1 = __uint_as_float(ua.x & 0xffff0000u);
          float c0 = __uint_as_float(ub.x << 16), c1 = __uint_as_float(ub.x & 0xffff0000u);
          afc.u.x = cvt_pk_bf16(fxa * a0 + fxb * c0, fxa * a1 + fxb * c1);
        }
        {
          float a0 = __uint_as_float(ua.y << 16), a1 = __uint_as_float(ua.y & 0xffff0000u);
          float c0 = __uint_as_float(ub.y << 16), c1 = __uint_as_float(ub.y & 0xffff0000u);
          afc.u.y = cvt_pk_bf16(fxa * a0 + fxb * c0, fxa * a1 + fxb * c1);
        }
        {
          float a0 = __uint_as_float(ua.z << 16), a1 = __uint_as_float(ua.z & 0xffff0000u);
          float c0 = __uint_as_float(ub.z << 16), c1 = __uint_as_float(ub.z & 0xffff0000u);
          afc.u.z = cvt_pk_bf16(fxa * a0 + fxb * c0, fxa * a1 + fxb * c1);
        }
        {
          float a0 = __uint_as_float(ua.w << 16), a1 = __uint_as_float(ua.w & 0xffff0000u);
          float c0 = __uint_as_float(ub.w << 16), c1 = __uint_as_float(ub.w & 0xffff0000u);
          afc.u.w = cvt_pk_bf16(fxa * a0 + fxb * c0, fxa * a1 + fxb * c1);
        }
        af[mi] = afc.v;
      }
      int ch0 = (tap * 8 + kk * 4 + quad) * 128 + (ng << 6);
#pragma unroll
      for (int ni = 0; ni < 4; ni++) {
        bf16x8 bf = kbase[ch0 + ni * 16 + l15];
        acc[0][ni] = __builtin_amdgcn_mfma_f32_16x16x32_bf16(af[0], bf, acc[0][ni], 0, 0, 0);
        acc[1][ni] = __builtin_amdgcn_mfma_f32_16x16x32_bf16(af[1], bf, acc[1][ni], 0, 0, 0);
      }
    }
    // no trailing barrier: next tap writes the OTHER buffer; every wave's
    // reads of buf[t] precede its barrier(t+1) in program order
  }

  // ---- epilogue, barrier-free: bias + relu (C/D: col=lane&15, row=quad*4+r) ----
  size_t outbase = ((size_t)(b * Hh + h) * Ww + w0);
#pragma unroll
  for (int ni = 0; ni < 4; ni++) {
    int f = (ng << 6) + ni * 16 + l15;
    float bv = bias[f];
#pragma unroll
    for (int mi = 0; mi < 2; mi++) {
#pragma unroll
      for (int r = 0; r < 4; r++) {
        int m = m_base + mi * 16 + quad * 4 + r;
        out[(outbase + m) * Ff + f] = fmaxf(acc[mi][ni][r] + bv, 0.f);
      }
    }
  }
}

extern "C" void kernel_launch(void* const* d_in, const int* in_sizes, int n_in,
                              void* d_out, int out_size, void* d_ws, size_t ws_size,
                              hipStream_t stream) {
  const float* in   = (const float*)d_in[0];
  const float* kmat = (const float*)d_in[1];
  const float* bias = (const float*)d_in[2];
  float* out = (float*)d_out;

  float* offtab = (float*)d_ws;
  unsigned short* kTB = (unsigned short*)((char*)d_ws + Hh * 9 * 2 * sizeof(float));
  if (ws_size < (size_t)(Hh * 9 * 2 * sizeof(float) + 128 * 576 * sizeof(unsigned short)))
    return;

  prep_kernel<<<288, 256, 0, stream>>>(kmat, offtab, kTB);
  fused_kernel<<<Bb * Hh * (Ww / 64), 256, 0, stream>>>(in, bias, kTB, offtab, out);
}

// Round 9
// 135.745 us; speedup vs baseline: 3.2715x; 1.2068x over previous
//
#include <hip/hip_runtime.h>
#include <math.h>

#define Bb 4
#define Hh 128
#define Ww 256
#define Cc 64
#define Ff 128
#define INH 130   // H+2
#define INW 258   // W+2

#define WSLOT 72   // shorts per slot: 64 bf16 + 8 pad = 144B
#define WPW 37     // slots per wave window: 0..35 data, 36 = zero slot

typedef __attribute__((ext_vector_type(8))) __bf16 bf16x8;
typedef __attribute__((ext_vector_type(4))) float floatx4;

__device__ __forceinline__ unsigned short f2bf(float f) {
  unsigned int u = __float_as_uint(f);
  unsigned int r = u + 0x7fffu + ((u >> 16) & 1u);   // RNE
  return (unsigned short)(r >> 16);
}

// v_cvt_pk_bf16_f32: D[15:0]=bf16(S0), D[31:16]=bf16(S1), RNE.
__device__ __forceinline__ unsigned int cvt_pk_bf16(float lo, float hi) {
  unsigned int r;
  asm("v_cvt_pk_bf16_f32 %0, %1, %2" : "=v"(r) : "v"(lo), "v"(hi));
  return r;
}

// ---------------------------------------------------------------------------
// Prep: kernel -> bf16 in MFMA-fragment order kTB[tap][kk][quad][f] (16B per
// (..,f) chunk -> B-frag loads are 16B/lane fully-coalesced), + fp64 offset
// table (fp32 would flip the ux>0 branch at h=0).
// ---------------------------------------------------------------------------
__global__ void prep_kernel(const float* __restrict__ kmat,
                            float* __restrict__ offtab,
                            unsigned short* __restrict__ kTB) {
  int gid = blockIdx.x * 256 + threadIdx.x;
  if (gid < 576 * 128) {
    int f = gid & 127;
    int k = gid >> 7;
    int tap = k >> 6;
    int r = k & 63;
    int kk = r >> 5;
    int quad = (r >> 3) & 3;
    int i = r & 7;
    int chunk = tap * 8 + kk * 4 + quad;
    kTB[((size_t)chunk * 128 + f) * 8 + i] = f2bf(kmat[gid]);
  }
  if (gid < Hh * 9) {
    int h = gid / 9;
    int j = gid - h * 9;
    const double pi = 3.14159265358979323846;
    double unit_w = 2.0 * pi / (double)Ww;
    double unit_h = pi / (2.0 * (double)Hh);
    double rho = tan(unit_w);
    double theta = ((double)(Ww / 2) - 0.5 * (double)Ww) * unit_w;
    double phi = ((double)Hh - (double)h) * unit_h;
    double cph = cos(phi), sph = sin(phi);
    double cth = cos(theta), sth = sin(theta);
    double pux = cph * cth, puy = sph, puz = cph * sth;
    double txx = puz, txy = 0.0, txz = -pux;
    double tyx = puy * txz - puz * txy;
    double tyy = puz * txx - pux * txz;
    double tyz = pux * txy - puy * txx;
    const int r0t[9] = {1, 1, 1, 0, 0, 0, -1, -1, -1};
    const int r1t[9] = {-1, 0, 1, -1, 0, 1, -1, 0, 1};
    auto proj = [&](int r0, int r1, double& xr, double& yr) {
      double ux = pux + rho * ((double)r0 * txx + (double)r1 * tyx);
      double uy = puy + rho * ((double)r0 * txy + (double)r1 * tyy);
      double uz = puz + rho * ((double)r0 * txz + (double)r1 * tyz);
      double base = atan2(uz, ux);
      double th;
      if (ux > 0.0)        th = base;
      else if (ux < 0.0)   th = (uz >= 0.0) ? base + pi : base - pi;
      else                 th = (uz > 0.0) ? pi * 0.5 : -pi * 0.5;
      double ph = asin(uy);
      xr = (th / pi + 1.0) * 0.5 * (double)Ww;
      yr = (1.0 - 2.0 * ph / pi) * (double)Hh;
    };
    double xc, yc, xj, yj;
    proj(0, 0, xc, yc);
    proj(r0t[j], r1t[j], xj, yj);
    offtab[gid * 2 + 0] = (float)(xj - xc);   // added to y (faithful swap)
    offtab[gid * 2 + 1] = (float)(yj - yc);   // added to x
  }
}

// ---------------------------------------------------------------------------
// Fused, ZERO-BARRIER, bf16 PRIVATE WINDOWS: R6's best-known skeleton
// (per (b,h,128-w tile), 4 waves, pure m-split, private y-blend window,
// same-wave in-order DS instead of any __syncthreads) with the window in
// bf16 (numerics + conflict-free 16B-task geometry HW-proven in R7/R8:
// absmax unchanged at 0.03125). LDS 40.4 -> 21.3 KB: R6 was silently
// LDS-capped at 3 blocks/CU (12 waves) with a 25% residency tail vs its
// grid; now exactly 4 blocks/CU = 16 waves/CU, zero tail. Cost: bf16
// unpack in the x-blend (~+200 VALU/tap, affordable at 31% VALUBusy).
// Unified regs ~114 <= 128 cap for 4 waves/SIMD.
// ---------------------------------------------------------------------------
__global__ __launch_bounds__(256, 4) void fused_kernel(
    const float* __restrict__ in, const float* __restrict__ bias,
    const unsigned short* __restrict__ kTB, const float* __restrict__ offtab,
    float* __restrict__ out) {
  __shared__ unsigned short winH[4 * WPW * WSLOT];   // 21,312 B -> 4 blocks/CU

  // XCD swizzle: each XCD gets one b and a contiguous h-range (~4.4MB == L2)
  int lidx = ((blockIdx.x & 7) << 7) | (blockIdx.x >> 3);
  int wt = lidx & 1;
  int h  = (lidx >> 1) & 127;
  int b  = lidx >> 8;
  int w0 = wt << 7;

  int tid  = threadIdx.x;
  int lane = tid & 63;
  int wave = tid >> 6;
  int m_base = wave << 5;          // wave owns w-rows m_base .. m_base+31
  int l15  = lane & 15;
  int quad = lane >> 4;

  unsigned short* win = &winH[wave * (WPW * WSLOT)];
  // zero the private zero-slot (slot 36): 144 B
  if (lane < 9) *(uint4*)&win[36 * WSLOT + lane * 8] = (uint4){0u, 0u, 0u, 0u};
  // no barrier: only this wave reads it; same-wave DS ops are in-order

  floatx4 acc[2][8];
#pragma unroll
  for (int i = 0; i < 2; i++)
#pragma unroll
    for (int j = 0; j < 8; j++) acc[i][j] = (floatx4){0.f, 0.f, 0.f, 0.f};

  const float* inb = in + (size_t)b * Hh * Ww * Cc;
  const bf16x8* kbase = (const bf16x8*)kTB;

  for (int tap = 0; tap < 9; tap++) {
    float off0 = offtab[(h * 9 + tap) * 2 + 0];
    float off1 = offtab[(h * 9 + tap) * 2 + 1];
    float dyk = (float)(tap / 3), dxk = (float)(tap % 3);

    // ---- y side (block-uniform): rows + weights, pad folded into weights ----
    float y = (float)h + dyk + off0;
    y = fminf(fmaxf(y, 0.f), (float)(INH - 1));
    int y0i = (int)floorf(y);
    int y1i = y0i + 1;
    y0i = min(max(y0i, 0), INH - 1);
    y1i = min(max(y1i, 0), INH - 1);
    float wy0 = (float)y1i - y;
    float wy1 = y - (float)y0i;
    if (!(y0i >= 1 && y0i <= Hh)) wy0 = 0.f;
    if (!(y1i >= 1 && y1i <= Hh)) wy1 = 0.f;
    const char* r0 = (const char*)(inb + (size_t)min(max(y0i - 1, 0), Hh - 1) * Ww * Cc);
    const char* r1 = (const char*)(inb + (size_t)min(max(y1i - 1, 0), Hh - 1) * Ww * Cc);

    // ---- x side: block-uniform frac + window base ----
    float xrep = (float)w0 + dxk + off1;
    float flo  = floorf(xrep);
    int jb = (int)flo - 1;
    float fr = xrep - flo;              // uniform frac across w (±1ulp, benign)
    float fxa = 1.f - fr, fxb = fr;

    // ---- per-lane slot pairs (local to this wave's window) ----
    int s0v[2], s1v[2];
#pragma unroll
    for (int mi = 0; mi < 2; mi++) {
      int wr = m_base + mi * 16 + l15;
      float x = (float)(w0 + wr) + dxk + off1;   // ref op order
      if (x < 0.f) x += (float)INW;
      if (x > (float)(INW - 1)) x -= (float)INW;
      int x0i = (int)floorf(x);
      int s = x0i - jb;
      if (s < 0) s += INW;              // single-wrap lanes -> mod lookup
      int ls = s - m_base;              // expected = (mi*16+l15)+1 in [1,33]
      bool ok = (unsigned)ls <= 34u;    // margin for ±1ulp jitter
      s0v[mi] = ok ? ls : 36;           // outside window -> zero slot (both)
      s1v[mi] = ok ? ls + 1 : 36;
    }

    // ---- fill OWN window with Y-BLEND (bf16): 36 slots x 8 ch-groups =
    //      288 tasks; coalesced loads (8 lanes x consecutive 32B of one
    //      column); ONE column read per slot; one 16B ds_write per task ----
#pragma unroll
    for (int it = 0; it < 5; it++) {
      int t = lane + (it << 6);
      if (it < 4 || lane < 32) {        // 288 tasks
        int ls = t >> 3;
        int c8f = (t & 7) << 3;                 // float channel base
        int col = jb + m_base + ls;             // global raw column
        if (col < 0) col += INW;
        if (col > INW - 1) col -= INW;          // col in [0,257]
        bool cok = ((unsigned)(col - 1) < (unsigned)Ww);
        unsigned offc = (((unsigned)((col - 1) & (Ww - 1))) << 8) + ((unsigned)c8f << 2);
        float wa = cok ? wy0 : 0.f;             // x-pad -> zero column
        float wb = cok ? wy1 : 0.f;
        float4 a0 = *(const float4*)(r0 + offc);
        float4 a1 = *(const float4*)(r0 + offc + 16);
        float4 b0 = *(const float4*)(r1 + offc);
        float4 b1 = *(const float4*)(r1 + offc + 16);
        uint4 st;
        st.x = cvt_pk_bf16(wa * a0.x + wb * b0.x, wa * a0.y + wb * b0.y);
        st.y = cvt_pk_bf16(wa * a0.z + wb * b0.z, wa * a0.w + wb * b0.w);
        st.z = cvt_pk_bf16(wa * a1.x + wb * b1.x, wa * a1.y + wb * b1.y);
        st.w = cvt_pk_bf16(wa * a1.z + wb * b1.z, wa * a1.w + wb * b1.w);
        *(uint4*)(&win[ls * WSLOT + ((t & 7) << 3)]) = st;   // ds_write_b128
      }
    }

    // ---- MFMA: A-frags x-blended (bf16 unpack) from OWN window (in-order
    //      DS = fill done); B-frags coalesced from L2-hot kTB ----
#pragma unroll
    for (int kk = 0; kk < 2; kk++) {
      int ch0 = (tap * 8 + kk * 4 + quad) * 128;
      bf16x8 af[2];
#pragma unroll
      for (int mi = 0; mi < 2; mi++) {
        uint4 ua = *(const uint4*)&win[s0v[mi] * WSLOT + kk * 32 + quad * 8];
        uint4 ub = *(const uint4*)&win[s1v[mi] * WSLOT + kk * 32 + quad * 8];
        union { uint4 u; bf16x8 v; } afc;
        {
          float a0 = __uint_as_float(ua.x << 16), a1 = __uint_as_float(ua.x & 0xffff0000u);
          float c0 = __uint_as_float(ub.x << 16), c1 = __uint_as_float(ub.x & 0xffff0000u);
          afc.u.x = cvt_pk_bf16(fxa * a0 + fxb * c0, fxa * a1 + fxb * c1);
        }
        {
          float a0 = __uint_as_float(ua.y << 16), a1 = __uint_as_float(ua.y & 0xffff0000u);
          float c0 = __uint_as_float(ub.y << 16), c1 = __uint_as_float(ub.y & 0xffff0000u);
          afc.u.y = cvt_pk_bf16(fxa * a0 + fxb * c0, fxa * a1 + fxb * c1);
        }
        {
          float a0 = __uint_as_float(ua.z << 16), a1 = __uint_as_float(ua.z & 0xffff0000u);
          float c0 = __uint_as_float(ub.z << 16), c1 = __uint_as_float(ub.z & 0xffff0000u);
          afc.u.z = cvt_pk_bf16(fxa * a0 + fxb * c0, fxa * a1 + fxb * c1);
        }
        {
          float a0 = __uint_as_float(ua.w << 16), a1 = __uint_as_float(ua.w & 0xffff0000u);
          float c0 = __uint_as_float(ub.w << 16), c1 = __uint_as_float(ub.w & 0xffff0000u);
          afc.u.w = cvt_pk_bf16(fxa * a0 + fxb * c0, fxa * a1 + fxb * c1);
        }
        af[mi] = afc.v;
      }
#pragma unroll
      for (int ni = 0; ni < 8; ni++) {
        bf16x8 bf = kbase[ch0 + ni * 16 + l15];
        acc[0][ni] = __builtin_amdgcn_mfma_f32_16x16x32_bf16(af[0], bf, acc[0][ni], 0, 0, 0);
        acc[1][ni] = __builtin_amdgcn_mfma_f32_16x16x32_bf16(af[1], bf, acc[1][ni], 0, 0, 0);
      }
    }
    // no barrier: next tap's fill overwrites only THIS wave's window after
    // this wave's reads (same-wave DS ops execute in issue order)
  }

  // ---- epilogue: bias + relu (C/D: col=lane&15, row=quad*4+r) ----
  size_t outbase = ((size_t)(b * Hh + h) * Ww + w0);
#pragma unroll
  for (int ni = 0; ni < 8; ni++) {
    int f = ni * 16 + l15;
    float bv = bias[f];
#pragma unroll
    for (int mi = 0; mi < 2; mi++) {
#pragma unroll
      for (int r = 0; r < 4; r++) {
        int m = m_base + mi * 16 + quad * 4 + r;
        out[(outbase + m) * Ff + f] = fmaxf(acc[mi][ni][r] + bv, 0.f);
      }
    }
  }
}

extern "C" void kernel_launch(void* const* d_in, const int* in_sizes, int n_in,
                              void* d_out, int out_size, void* d_ws, size_t ws_size,
                              hipStream_t stream) {
  const float* in   = (const float*)d_in[0];
  const float* kmat = (const float*)d_in[1];
  const float* bias = (const float*)d_in[2];
  float* out = (float*)d_out;

  float* offtab = (float*)d_ws;
  unsigned short* kTB = (unsigned short*)((char*)d_ws + Hh * 9 * 2 * sizeof(float));
  if (ws_size < (size_t)(Hh * 9 * 2 * sizeof(float) + 128 * 576 * sizeof(unsigned short)))
    return;

  prep_kernel<<<288, 256, 0, stream>>>(kmat, offtab, kTB);
  fused_kernel<<<Bb * Hh * (Ww / 128), 256, 0, stream>>>(in, bias, kTB, offtab, out);
}